// Round 2
// baseline (278.839 us; speedup 1.0000x reference)
//
#include <hip/hip_runtime.h>
#include <math.h>

// ---- problem constants ----
#define NUM_CLASSES 80
#define APS_ 3
#define BB 64
#define NN 32
constexpr int G0s = 52, G1s = 26, G2s = 13;
constexpr int R0 = BB * G0s * G0s * APS_;   // 519168 rows (scale 0)
constexpr int R1 = BB * G1s * G1s * APS_;   // 129792 rows (scale 1)
constexpr int R2 = BB * G2s * G2s * APS_;   //  32448 rows (scale 2)
constexpr int MROWS = R0 + R1 + R2;         // 681408 total rows
constexpr int CH = 5 + NUM_CLASSES;         // 85

// grids
constexpr int OBJ_BLOCKS   = (BB * NN) / 4;      // 512 blocks carry obj terms (4 waves/block, 1 box/wave)
constexpr int MAIN_BLOCKS  = 1024;               // exactly 4 blocks/CU on 256 CUs — balanced
constexpr int NTHREADS     = MAIN_BLOCKS * 256;  // 262144; rows per thread = 2 or 3 (grid-stride)

// ws layout (floats):
// [0*OBJ_BLOCKS .. )   coord partial per obj-block        (512)
// [1*OBJ_BLOCKS .. )   conf-correction partial            (512)
// [2*OBJ_BLOCKS .. )   class partial                      (512)
// [3*OBJ_BLOCKS .. )   n_obj count partial                (512)
// [WS_SP_OFF    .. )   softplus(p4) partial per main-block (1024)
// [WS_CTR_OFF   ]      block-completion counter (uint, memset to 0 pre-launch)
constexpr int WS_SP_OFF  = 4 * OBJ_BLOCKS;
constexpr int WS_CTR_OFF = WS_SP_OFF + MAIN_BLOCKS;

__device__ __forceinline__ float softplusf(float x) {
    // == max(x,0) + log1p(exp(-|x|)) : exactly the bce(x,0) formula
    return fmaxf(x, 0.0f) + log1pf(expf(-fabsf(x)));
}

// channel-4 address of global row r (rows concatenated p0|p1|p2)
__device__ __forceinline__ const float* ch4_addr(const float* __restrict__ p0,
                                                 const float* __restrict__ p1,
                                                 const float* __restrict__ p2,
                                                 int r) {
    const float* p;
    int rr;
    if (r < R0)            { p = p0; rr = r; }
    else if (r < R0 + R1)  { p = p1; rr = r - R0; }
    else                   { p = p2; rr = r - R0 - R1; }
    return p + (size_t)rr * CH + 4;
}

// key-only assignment (for dedup scans): scale, anchor-in-scale, cell iy/ix
__device__ __forceinline__ void box_key(const float* __restrict__ bboxes,
                                        const float* __restrict__ anchors,
                                        int b, int n,
                                        int& s, int& a, int& iy, int& ix) {
    const float* q = bboxes + (size_t)(b * NN + n) * 4;
    float x = q[0], y = q[1], w = q[2], h = q[3];
    float cx = x + w * 0.5f, cy = y + h * 0.5f;
    int best = 0;
    float bestd = 1e30f;
#pragma unroll
    for (int i = 0; i < 9; i++) {
        float d = fabsf(w - anchors[2 * i]) + fabsf(h - anchors[2 * i + 1]);
        if (d < bestd) { bestd = d; best = i; }   // strict < : first-min like argmin
    }
    s = best / 3;
    a = best - s * 3;
    int G = (s == 0) ? G0s : (s == 1) ? G1s : G2s;
    float cell = 1.0f / (float)G;                  // match ref: floor(cxy / cell)
    ix = (int)floorf(cx / cell);
    iy = (int)floorf(cy / cell);
}

// Fully fused kernel:
//  - ALL blocks: scattered channel-4 gather -> softplus partial (grid-stride,
//    stride = NTHREADS so each wave instruction reads 64 consecutive rows;
//    non-temporal — 43.6 MB streamed once, zero reuse).
//  - blocks < OBJ_BLOCKS: additionally one box per wave (obj terms), zero atomics.
//  - LAST finishing block (device-scope atomic counter, fence-ordered) reduces
//    all per-block partials and writes the 4 outputs — no second kernel.
__global__ void k_main(const float* __restrict__ p0, const float* __restrict__ p1,
                       const float* __restrict__ p2,
                       const float* __restrict__ bboxes,
                       const int* __restrict__ labels,
                       const float* __restrict__ anchors,
                       float* __restrict__ ws,
                       float* __restrict__ out) {
    int lane = threadIdx.x & 63;
    int wav  = threadIdx.x >> 6;

    // ---------------- bulk gather: softplus(pred[row][4]) ----------------
    int gtid = blockIdx.x * 256 + threadIdx.x;
    // rows: gtid, gtid+NT, gtid+2*NT (third conditional). Issue ALL loads
    // before any softplus so HBM latency overlaps.
    int r3 = gtid + 2 * NTHREADS;
    bool has3 = (r3 < MROWS);
    const float* a1 = ch4_addr(p0, p1, p2, gtid);
    const float* a2 = ch4_addr(p0, p1, p2, gtid + NTHREADS);
    const float* a3 = ch4_addr(p0, p1, p2, has3 ? r3 : gtid);  // safe dup addr when absent
    float v1 = __builtin_nontemporal_load(a1);
    float v2 = __builtin_nontemporal_load(a2);
    float v3 = __builtin_nontemporal_load(a3);
    float sp = softplusf(v1) + softplusf(v2) + (has3 ? softplusf(v3) : 0.0f);

    // ---------------- obj terms (first OBJ_BLOCKS blocks only) ----------------
    float coordp = 0.0f, confp = 0.0f, clsp = 0.0f;
    bool superseded = true;   // superseded==true contributes nothing / count 0
    if (blockIdx.x < OBJ_BLOCKS) {
        int wid = blockIdx.x * 4 + wav;           // box id, < BB*NN
        int b = wid / NN, n = wid - b * NN;

        int s, a, iy, ix;
        box_key(bboxes, anchors, b, n, s, a, iy, ix);

        // dedup: lane l probes box n+1+l of the same image; identical key means
        // a LATER box overwrites this target row (numpy last-write-wins).
        int n2 = n + 1 + lane;
        int match = 0;
        if (n2 < NN) {
            int s2, a2i, iy2, ix2;
            box_key(bboxes, anchors, b, n2, s2, a2i, iy2, ix2);
            match = (s2 == s) & (a2i == a) & (iy2 == iy) & (ix2 == ix);
        }
        superseded = __any(match);

        if (!superseded) {
            const float* q = bboxes + (size_t)(b * NN + n) * 4;
            float x = q[0], y = q[1], w = q[2], h = q[3];
            float cx = x + w * 0.5f, cy = y + h * 0.5f;
            int G = (s == 0) ? G0s : (s == 1) ? G1s : G2s;
            float cell = 1.0f / (float)G;
            float fx = (cx - (float)ix * cell) / cell + 1e-8f;
            float fy = (cy - (float)iy * cell) / cell + 1e-8f;
            float tx = -logf(1.0f / fx - 1.0f);
            float ty = -logf(1.0f / fy - 1.0f);
            int prior = s * 3 + a;
            float tw = logf(w / anchors[2 * prior]);
            float th = logf(h / anchors[2 * prior + 1]);
            int lab = labels[b * NN + n];

            const float* ps = (s == 0) ? p0 : (s == 1) ? p1 : p2;
            int row = ((b * G + iy) * G + ix) * APS_ + a;
            const float* prow = ps + (size_t)row * CH;

#pragma unroll
            for (int pass = 0; pass < 2; pass++) {
                int ch = lane + pass * 64;
                if (ch < CH) {
                    float p = prow[ch];
                    if (ch < 4) {
                        float tt = (ch == 0) ? tx : (ch == 1) ? ty : (ch == 2) ? tw : th;
                        float d = p - tt;
                        coordp += d * d;
                    } else if (ch == 4) {
                        confp += -p;   // bce(x,1) - bce(x,0) = -x
                    } else {
                        clsp += softplusf(p) - (((ch - 5) == lab) ? p : 0.0f);
                    }
                }
            }
        }
    }

    // ---------------- block reduction -> ws partials ----------------
#pragma unroll
    for (int o = 32; o > 0; o >>= 1) {
        sp     += __shfl_down(sp,     o);
        coordp += __shfl_down(coordp, o);
        confp  += __shfl_down(confp,  o);
        clsp   += __shfl_down(clsp,   o);
    }

    __shared__ float sm[4][5];   // [wave][sp,coord,conf,cls,cnt]
    __shared__ int   s_last;
    if (lane == 0) {
        sm[wav][0] = sp;
        sm[wav][1] = coordp;
        sm[wav][2] = confp;
        sm[wav][3] = clsp;
        sm[wav][4] = superseded ? 0.0f : 1.0f;
    }
    __syncthreads();
    if (threadIdx.x == 0) {
        ws[WS_SP_OFF + blockIdx.x] = sm[0][0] + sm[1][0] + sm[2][0] + sm[3][0];
        if (blockIdx.x < OBJ_BLOCKS) {
            ws[0 * OBJ_BLOCKS + blockIdx.x] = sm[0][1] + sm[1][1] + sm[2][1] + sm[3][1];
            ws[1 * OBJ_BLOCKS + blockIdx.x] = sm[0][2] + sm[1][2] + sm[2][2] + sm[3][2];
            ws[2 * OBJ_BLOCKS + blockIdx.x] = sm[0][3] + sm[1][3] + sm[2][3] + sm[3][3];
            ws[3 * OBJ_BLOCKS + blockIdx.x] = sm[0][4] + sm[1][4] + sm[2][4] + sm[3][4];
        }
        // release our partials, then count in (device-scope atomic)
        __threadfence();
        unsigned old = atomicAdd((unsigned*)(ws + WS_CTR_OFF), 1u);
        s_last = (old == (unsigned)(MAIN_BLOCKS - 1)) ? 1 : 0;
    }
    __syncthreads();
    if (!s_last) return;

    // ---------------- last block: final reduction ----------------
    __threadfence();   // acquire: all other blocks' partials now visible
    float coord_s = 0.0f, confc_s = 0.0f, cls_s = 0.0f, cnt_s = 0.0f, sp_s = 0.0f;
    for (int i = threadIdx.x; i < OBJ_BLOCKS; i += 256) {
        coord_s += ws[0 * OBJ_BLOCKS + i];
        confc_s += ws[1 * OBJ_BLOCKS + i];
        cls_s   += ws[2 * OBJ_BLOCKS + i];
        cnt_s   += ws[3 * OBJ_BLOCKS + i];
    }
    for (int i = threadIdx.x; i < MAIN_BLOCKS; i += 256) {
        sp_s += ws[WS_SP_OFF + i];
    }
#pragma unroll
    for (int o = 32; o > 0; o >>= 1) {
        coord_s += __shfl_down(coord_s, o);
        confc_s += __shfl_down(confc_s, o);
        cls_s   += __shfl_down(cls_s,   o);
        cnt_s   += __shfl_down(cnt_s,   o);
        sp_s    += __shfl_down(sp_s,    o);
    }
    __shared__ float ls[4][5];
    if (lane == 0) {
        ls[wav][0] = coord_s; ls[wav][1] = confc_s; ls[wav][2] = cls_s;
        ls[wav][3] = cnt_s;   ls[wav][4] = sp_s;
    }
    __syncthreads();
    if (threadIdx.x == 0) {
        float coord = ls[0][0] + ls[1][0] + ls[2][0] + ls[3][0];
        float confc = ls[0][1] + ls[1][1] + ls[2][1] + ls[3][1];
        float cls   = ls[0][2] + ls[1][2] + ls[2][2] + ls[3][2];
        float cnt   = ls[0][3] + ls[1][3] + ls[2][3] + ls[3][3];
        float spv   = ls[0][4] + ls[1][4] + ls[2][4] + ls[3][4];
        float n_obj = fmaxf(cnt, 1.0f);
        float coord_loss = 0.05f * coord / (n_obj * 4.0f);
        float conf_loss  = (spv + confc) / (float)MROWS;
        float class_loss = 0.5f * cls / (n_obj * (float)NUM_CLASSES);
        out[0] = coord_loss + conf_loss + class_loss;
        out[1] = coord_loss;
        out[2] = conf_loss;
        out[3] = class_loss;
    }
}

extern "C" void kernel_launch(void* const* d_in, const int* in_sizes, int n_in,
                              void* d_out, int out_size, void* d_ws, size_t ws_size,
                              hipStream_t stream) {
    const float* p0      = (const float*)d_in[0];
    const float* p1      = (const float*)d_in[1];
    const float* p2      = (const float*)d_in[2];
    const float* bboxes  = (const float*)d_in[3];
    const int*   labels  = (const int*)d_in[4];
    const float* anchors = (const float*)d_in[5];
    float* ws  = (float*)d_ws;
    float* out = (float*)d_out;

    // init the completion counter (capturable async memset node, 4 bytes)
    hipMemsetAsync(ws + WS_CTR_OFF, 0, sizeof(unsigned), stream);
    k_main<<<MAIN_BLOCKS, 256, 0, stream>>>(p0, p1, p2, bboxes, labels, anchors, ws, out);
}

// Round 3
// 252.088 us; speedup vs baseline: 1.1061x; 1.1061x over previous
//
#include <hip/hip_runtime.h>
#include <math.h>

// ---- problem constants ----
#define NUM_CLASSES 80
#define APS_ 3
#define BB 64
#define NN 32
constexpr int G0s = 52, G1s = 26, G2s = 13;
constexpr int R0 = BB * G0s * G0s * APS_;   // 519168 rows (scale 0)
constexpr int R1 = BB * G1s * G1s * APS_;   // 129792 rows (scale 1)
constexpr int R2 = BB * G2s * G2s * APS_;   //  32448 rows (scale 2)
constexpr int MROWS = R0 + R1 + R2;         // 681408 total rows
constexpr int CH = 5 + NUM_CLASSES;         // 85

// grids
constexpr int OBJ_BLOCKS   = (BB * NN) / 4;      // 512 blocks carry obj terms (4 waves/block, 1 box/wave)
constexpr int MAIN_BLOCKS  = 1024;               // exactly 4 blocks/CU on 256 CUs — balanced
constexpr int NTHREADS     = MAIN_BLOCKS * 256;  // 262144; rows per thread = 2 or 3 (grid-stride)

// ws layout (floats), all plain-stored (fully overwritten every call -> no init):
// [0*OBJ_BLOCKS .. )   coord partial per obj-block        (512)
// [1*OBJ_BLOCKS .. )   conf-correction partial            (512)
// [2*OBJ_BLOCKS .. )   class partial                      (512)
// [3*OBJ_BLOCKS .. )   n_obj count partial                (512)
// [WS_SP_OFF    .. )   softplus(p4) partial per main-block (1024)
constexpr int WS_SP_OFF = 4 * OBJ_BLOCKS;

__device__ __forceinline__ float softplusf(float x) {
    // == max(x,0) + log1p(exp(-|x|)) : exactly the bce(x,0) formula
    return fmaxf(x, 0.0f) + log1pf(expf(-fabsf(x)));
}

// channel-4 address of global row r (rows concatenated p0|p1|p2)
__device__ __forceinline__ const float* ch4_addr(const float* __restrict__ p0,
                                                 const float* __restrict__ p1,
                                                 const float* __restrict__ p2,
                                                 int r) {
    const float* p;
    int rr;
    if (r < R0)            { p = p0; rr = r; }
    else if (r < R0 + R1)  { p = p1; rr = r - R0; }
    else                   { p = p2; rr = r - R0 - R1; }
    return p + (size_t)rr * CH + 4;
}

// key-only assignment (for dedup scans): scale, anchor-in-scale, cell iy/ix
__device__ __forceinline__ void box_key(const float* __restrict__ bboxes,
                                        const float* __restrict__ anchors,
                                        int b, int n,
                                        int& s, int& a, int& iy, int& ix) {
    const float* q = bboxes + (size_t)(b * NN + n) * 4;
    float x = q[0], y = q[1], w = q[2], h = q[3];
    float cx = x + w * 0.5f, cy = y + h * 0.5f;
    int best = 0;
    float bestd = 1e30f;
#pragma unroll
    for (int i = 0; i < 9; i++) {
        float d = fabsf(w - anchors[2 * i]) + fabsf(h - anchors[2 * i + 1]);
        if (d < bestd) { bestd = d; best = i; }   // strict < : first-min like argmin
    }
    s = best / 3;
    a = best - s * 3;
    int G = (s == 0) ? G0s : (s == 1) ? G1s : G2s;
    float cell = 1.0f / (float)G;                  // match ref: floor(cxy / cell)
    ix = (int)floorf(cx / cell);
    iy = (int)floorf(cy / cell);
}

// Fused main kernel (R1 structure — no device fences/atomics; the last-block
// fused variant regressed +31us from cross-XCD fence traffic):
//  - ALL blocks: scattered channel-4 gather -> softplus partial (grid-stride,
//    stride = NTHREADS so each wave instruction reads 64 consecutive rows;
//    non-temporal — 43.6 MB streamed once, zero reuse).
//  - blocks < OBJ_BLOCKS: additionally one box per wave (obj terms), zero atomics.
__global__ void k_main(const float* __restrict__ p0, const float* __restrict__ p1,
                       const float* __restrict__ p2,
                       const float* __restrict__ bboxes,
                       const int* __restrict__ labels,
                       const float* __restrict__ anchors,
                       float* __restrict__ ws) {
    int lane = threadIdx.x & 63;
    int wav  = threadIdx.x >> 6;

    // ---------------- bulk gather: softplus(pred[row][4]) ----------------
    int gtid = blockIdx.x * 256 + threadIdx.x;
    // rows: gtid, gtid+NT, gtid+2*NT (third conditional). Issue ALL loads
    // before any softplus so HBM latency overlaps.
    int r3 = gtid + 2 * NTHREADS;
    bool has3 = (r3 < MROWS);
    const float* a1 = ch4_addr(p0, p1, p2, gtid);
    const float* a2 = ch4_addr(p0, p1, p2, gtid + NTHREADS);
    const float* a3 = ch4_addr(p0, p1, p2, has3 ? r3 : gtid);  // safe dup addr when absent
    float v1 = __builtin_nontemporal_load(a1);
    float v2 = __builtin_nontemporal_load(a2);
    float v3 = __builtin_nontemporal_load(a3);
    float sp = softplusf(v1) + softplusf(v2) + (has3 ? softplusf(v3) : 0.0f);

    // ---------------- obj terms (first OBJ_BLOCKS blocks only) ----------------
    float coordp = 0.0f, confp = 0.0f, clsp = 0.0f;
    bool superseded = true;   // superseded==true contributes nothing / count 0
    if (blockIdx.x < OBJ_BLOCKS) {
        int wid = blockIdx.x * 4 + wav;           // box id, < BB*NN
        int b = wid / NN, n = wid - b * NN;

        int s, a, iy, ix;
        box_key(bboxes, anchors, b, n, s, a, iy, ix);

        // dedup: lane l probes box n+1+l of the same image; identical key means
        // a LATER box overwrites this target row (numpy last-write-wins).
        int n2 = n + 1 + lane;
        int match = 0;
        if (n2 < NN) {
            int s2, a2i, iy2, ix2;
            box_key(bboxes, anchors, b, n2, s2, a2i, iy2, ix2);
            match = (s2 == s) & (a2i == a) & (iy2 == iy) & (ix2 == ix);
        }
        superseded = __any(match);

        if (!superseded) {
            const float* q = bboxes + (size_t)(b * NN + n) * 4;
            float x = q[0], y = q[1], w = q[2], h = q[3];
            float cx = x + w * 0.5f, cy = y + h * 0.5f;
            int G = (s == 0) ? G0s : (s == 1) ? G1s : G2s;
            float cell = 1.0f / (float)G;
            float fx = (cx - (float)ix * cell) / cell + 1e-8f;
            float fy = (cy - (float)iy * cell) / cell + 1e-8f;
            float tx = -logf(1.0f / fx - 1.0f);
            float ty = -logf(1.0f / fy - 1.0f);
            int prior = s * 3 + a;
            float tw = logf(w / anchors[2 * prior]);
            float th = logf(h / anchors[2 * prior + 1]);
            int lab = labels[b * NN + n];

            const float* ps = (s == 0) ? p0 : (s == 1) ? p1 : p2;
            int row = ((b * G + iy) * G + ix) * APS_ + a;
            const float* prow = ps + (size_t)row * CH;

#pragma unroll
            for (int pass = 0; pass < 2; pass++) {
                int ch = lane + pass * 64;
                if (ch < CH) {
                    float p = prow[ch];
                    if (ch < 4) {
                        float tt = (ch == 0) ? tx : (ch == 1) ? ty : (ch == 2) ? tw : th;
                        float d = p - tt;
                        coordp += d * d;
                    } else if (ch == 4) {
                        confp += -p;   // bce(x,1) - bce(x,0) = -x
                    } else {
                        clsp += softplusf(p) - (((ch - 5) == lab) ? p : 0.0f);
                    }
                }
            }
        }
    }

    // ---------------- reductions ----------------
#pragma unroll
    for (int o = 32; o > 0; o >>= 1) {
        sp     += __shfl_down(sp,     o);
        coordp += __shfl_down(coordp, o);
        confp  += __shfl_down(confp,  o);
        clsp   += __shfl_down(clsp,   o);
    }

    __shared__ float sm[4][5];   // [wave][sp,coord,conf,cls,cnt]
    if (lane == 0) {
        sm[wav][0] = sp;
        sm[wav][1] = coordp;
        sm[wav][2] = confp;
        sm[wav][3] = clsp;
        sm[wav][4] = superseded ? 0.0f : 1.0f;
    }
    __syncthreads();
    if (threadIdx.x == 0) {
        ws[WS_SP_OFF + blockIdx.x] = sm[0][0] + sm[1][0] + sm[2][0] + sm[3][0];
        if (blockIdx.x < OBJ_BLOCKS) {
            ws[0 * OBJ_BLOCKS + blockIdx.x] = sm[0][1] + sm[1][1] + sm[2][1] + sm[3][1];
            ws[1 * OBJ_BLOCKS + blockIdx.x] = sm[0][2] + sm[1][2] + sm[2][2] + sm[3][2];
            ws[2 * OBJ_BLOCKS + blockIdx.x] = sm[0][3] + sm[1][3] + sm[2][3] + sm[3][3];
            ws[3 * OBJ_BLOCKS + blockIdx.x] = sm[0][4] + sm[1][4] + sm[2][4] + sm[3][4];
        }
    }
}

// final: ONE WAVE (64 lanes) reduces all partials — pure shuffle, no LDS/syncs.
__global__ void k_fin(const float* __restrict__ ws, float* __restrict__ out) {
    float coord_s = 0.0f, confc_s = 0.0f, cls_s = 0.0f, cnt_s = 0.0f, sp_s = 0.0f;
    for (int i = threadIdx.x; i < OBJ_BLOCKS; i += 64) {
        coord_s += ws[0 * OBJ_BLOCKS + i];
        confc_s += ws[1 * OBJ_BLOCKS + i];
        cls_s   += ws[2 * OBJ_BLOCKS + i];
        cnt_s   += ws[3 * OBJ_BLOCKS + i];
    }
    for (int i = threadIdx.x; i < MAIN_BLOCKS; i += 64) {
        sp_s += ws[WS_SP_OFF + i];
    }
#pragma unroll
    for (int o = 32; o > 0; o >>= 1) {
        coord_s += __shfl_down(coord_s, o);
        confc_s += __shfl_down(confc_s, o);
        cls_s   += __shfl_down(cls_s,   o);
        cnt_s   += __shfl_down(cnt_s,   o);
        sp_s    += __shfl_down(sp_s,    o);
    }
    if (threadIdx.x == 0) {
        float n_obj = fmaxf(cnt_s, 1.0f);
        float coord_loss = 0.05f * coord_s / (n_obj * 4.0f);
        float conf_loss  = (sp_s + confc_s) / (float)MROWS;
        float class_loss = 0.5f * cls_s / (n_obj * (float)NUM_CLASSES);
        out[0] = coord_loss + conf_loss + class_loss;
        out[1] = coord_loss;
        out[2] = conf_loss;
        out[3] = class_loss;
    }
}

extern "C" void kernel_launch(void* const* d_in, const int* in_sizes, int n_in,
                              void* d_out, int out_size, void* d_ws, size_t ws_size,
                              hipStream_t stream) {
    const float* p0      = (const float*)d_in[0];
    const float* p1      = (const float*)d_in[1];
    const float* p2      = (const float*)d_in[2];
    const float* bboxes  = (const float*)d_in[3];
    const int*   labels  = (const int*)d_in[4];
    const float* anchors = (const float*)d_in[5];
    float* ws  = (float*)d_ws;
    float* out = (float*)d_out;

    k_main<<<MAIN_BLOCKS, 256, 0, stream>>>(p0, p1, p2, bboxes, labels, anchors, ws);
    k_fin<<<1, 64, 0, stream>>>(ws, out);
}

// Round 5
// 247.687 us; speedup vs baseline: 1.1258x; 1.0178x over previous
//
#include <hip/hip_runtime.h>
#include <math.h>

// ---- problem constants ----
#define NUM_CLASSES 80
#define APS_ 3
#define BB 64
#define NN 32
constexpr int G0s = 52, G1s = 26, G2s = 13;
constexpr int R0 = BB * G0s * G0s * APS_;   // 519168 rows (scale 0)
constexpr int R1 = BB * G1s * G1s * APS_;   // 129792 rows (scale 1)
constexpr int R2 = BB * G2s * G2s * APS_;   //  32448 rows (scale 2)
constexpr int MROWS = R0 + R1 + R2;         // 681408 total rows
constexpr int CH = 5 + NUM_CLASSES;         // 85

// grids
constexpr int OBJ_BLOCKS   = (BB * NN) / 4;      // 512 blocks carry obj terms (4 waves/block, 1 box/wave)
constexpr int MAIN_BLOCKS  = 1024;               // exactly 4 blocks/CU on 256 CUs — balanced
constexpr int NTHREADS     = MAIN_BLOCKS * 256;  // 262144; rows per thread = 2 or 3 (grid-stride)

// ws layout (floats), all plain-stored (fully overwritten every call -> no init):
// [0*OBJ_BLOCKS .. )   coord partial per obj-block        (512)
// [1*OBJ_BLOCKS .. )   conf-correction partial            (512)
// [2*OBJ_BLOCKS .. )   class partial                      (512)
// [3*OBJ_BLOCKS .. )   n_obj count partial                (512)
// [WS_SP_OFF    .. )   softplus(p4) partial per main-block (1024)
constexpr int WS_SP_OFF = 4 * OBJ_BLOCKS;

__device__ __forceinline__ float softplusf(float x) {
    // == max(x,0) + log1p(exp(-|x|)) : exactly the bce(x,0) formula
    return fmaxf(x, 0.0f) + log1pf(expf(-fabsf(x)));
}

// channel-4 address of global row r (rows concatenated p0|p1|p2)
__device__ __forceinline__ const float* ch4_addr(const float* __restrict__ p0,
                                                 const float* __restrict__ p1,
                                                 const float* __restrict__ p2,
                                                 int r) {
    const float* p;
    int rr;
    if (r < R0)            { p = p0; rr = r; }
    else if (r < R0 + R1)  { p = p1; rr = r - R0; }
    else                   { p = p2; rr = r - R0 - R1; }
    return p + (size_t)rr * CH + 4;
}

// key-only assignment (for dedup scans): scale, anchor-in-scale, cell iy/ix
__device__ __forceinline__ void box_key(const float* __restrict__ bboxes,
                                        const float* __restrict__ anchors,
                                        int b, int n,
                                        int& s, int& a, int& iy, int& ix) {
    const float* q = bboxes + (size_t)(b * NN + n) * 4;
    float x = q[0], y = q[1], w = q[2], h = q[3];
    float cx = x + w * 0.5f, cy = y + h * 0.5f;
    int best = 0;
    float bestd = 1e30f;
#pragma unroll
    for (int i = 0; i < 9; i++) {
        float d = fabsf(w - anchors[2 * i]) + fabsf(h - anchors[2 * i + 1]);
        if (d < bestd) { bestd = d; best = i; }   // strict < : first-min like argmin
    }
    s = best / 3;
    a = best - s * 3;
    int G = (s == 0) ? G0s : (s == 1) ? G1s : G2s;
    float cell = 1.0f / (float)G;                  // match ref: floor(cxy / cell)
    ix = (int)floorf(cx / cell);
    iy = (int)floorf(cy / cell);
}

// Fused main kernel (R1 structure — no device fences/atomics; the last-block
// fused variant regressed +31us from cross-XCD fence traffic):
//  - ALL blocks: scattered channel-4 gather -> softplus partial (grid-stride,
//    stride = NTHREADS so each wave instruction reads 64 consecutive rows;
//    non-temporal — 43.6 MB streamed once, zero reuse).
//  - blocks < OBJ_BLOCKS: additionally one box per wave (obj terms), zero atomics.
__global__ void k_main(const float* __restrict__ p0, const float* __restrict__ p1,
                       const float* __restrict__ p2,
                       const float* __restrict__ bboxes,
                       const int* __restrict__ labels,
                       const float* __restrict__ anchors,
                       float* __restrict__ ws) {
    int lane = threadIdx.x & 63;
    int wav  = threadIdx.x >> 6;

    // ---------------- bulk gather: softplus(pred[row][4]) ----------------
    int gtid = blockIdx.x * 256 + threadIdx.x;
    // rows: gtid, gtid+NT, gtid+2*NT (third conditional). Issue ALL loads
    // before any softplus so HBM latency overlaps.
    int r3 = gtid + 2 * NTHREADS;
    bool has3 = (r3 < MROWS);
    const float* a1 = ch4_addr(p0, p1, p2, gtid);
    const float* a2 = ch4_addr(p0, p1, p2, gtid + NTHREADS);
    const float* a3 = ch4_addr(p0, p1, p2, has3 ? r3 : gtid);  // safe dup addr when absent
    float v1 = __builtin_nontemporal_load(a1);
    float v2 = __builtin_nontemporal_load(a2);
    float v3 = __builtin_nontemporal_load(a3);
    float sp = softplusf(v1) + softplusf(v2) + (has3 ? softplusf(v3) : 0.0f);

    // ---------------- obj terms (first OBJ_BLOCKS blocks only) ----------------
    float coordp = 0.0f, confp = 0.0f, clsp = 0.0f;
    bool superseded = true;   // superseded==true contributes nothing / count 0
    if (blockIdx.x < OBJ_BLOCKS) {
        int wid = blockIdx.x * 4 + wav;           // box id, < BB*NN
        int b = wid / NN, n = wid - b * NN;

        int s, a, iy, ix;
        box_key(bboxes, anchors, b, n, s, a, iy, ix);

        // dedup: lane l probes box n+1+l of the same image; identical key means
        // a LATER box overwrites this target row (numpy last-write-wins).
        int n2 = n + 1 + lane;
        int match = 0;
        if (n2 < NN) {
            int s2, a2i, iy2, ix2;
            box_key(bboxes, anchors, b, n2, s2, a2i, iy2, ix2);
            match = (s2 == s) & (a2i == a) & (iy2 == iy) & (ix2 == ix);
        }
        superseded = __any(match);

        if (!superseded) {
            const float* q = bboxes + (size_t)(b * NN + n) * 4;
            float x = q[0], y = q[1], w = q[2], h = q[3];
            float cx = x + w * 0.5f, cy = y + h * 0.5f;
            int G = (s == 0) ? G0s : (s == 1) ? G1s : G2s;
            float cell = 1.0f / (float)G;
            float fx = (cx - (float)ix * cell) / cell + 1e-8f;
            float fy = (cy - (float)iy * cell) / cell + 1e-8f;
            float tx = -logf(1.0f / fx - 1.0f);
            float ty = -logf(1.0f / fy - 1.0f);
            int prior = s * 3 + a;
            float tw = logf(w / anchors[2 * prior]);
            float th = logf(h / anchors[2 * prior + 1]);
            int lab = labels[b * NN + n];

            const float* ps = (s == 0) ? p0 : (s == 1) ? p1 : p2;
            int row = ((b * G + iy) * G + ix) * APS_ + a;
            const float* prow = ps + (size_t)row * CH;

#pragma unroll
            for (int pass = 0; pass < 2; pass++) {
                int ch = lane + pass * 64;
                if (ch < CH) {
                    float p = prow[ch];
                    if (ch < 4) {
                        float tt = (ch == 0) ? tx : (ch == 1) ? ty : (ch == 2) ? tw : th;
                        float d = p - tt;
                        coordp += d * d;
                    } else if (ch == 4) {
                        confp += -p;   // bce(x,1) - bce(x,0) = -x
                    } else {
                        clsp += softplusf(p) - (((ch - 5) == lab) ? p : 0.0f);
                    }
                }
            }
        }
    }

    // ---------------- reductions ----------------
#pragma unroll
    for (int o = 32; o > 0; o >>= 1) {
        sp     += __shfl_down(sp,     o);
        coordp += __shfl_down(coordp, o);
        confp  += __shfl_down(confp,  o);
        clsp   += __shfl_down(clsp,   o);
    }

    __shared__ float sm[4][5];   // [wave][sp,coord,conf,cls,cnt]
    if (lane == 0) {
        sm[wav][0] = sp;
        sm[wav][1] = coordp;
        sm[wav][2] = confp;
        sm[wav][3] = clsp;
        sm[wav][4] = superseded ? 0.0f : 1.0f;
    }
    __syncthreads();
    if (threadIdx.x == 0) {
        ws[WS_SP_OFF + blockIdx.x] = sm[0][0] + sm[1][0] + sm[2][0] + sm[3][0];
        if (blockIdx.x < OBJ_BLOCKS) {
            ws[0 * OBJ_BLOCKS + blockIdx.x] = sm[0][1] + sm[1][1] + sm[2][1] + sm[3][1];
            ws[1 * OBJ_BLOCKS + blockIdx.x] = sm[0][2] + sm[1][2] + sm[2][2] + sm[3][2];
            ws[2 * OBJ_BLOCKS + blockIdx.x] = sm[0][3] + sm[1][3] + sm[2][3] + sm[3][3];
            ws[3 * OBJ_BLOCKS + blockIdx.x] = sm[0][4] + sm[1][4] + sm[2][4] + sm[3][4];
        }
    }
}

// final: one block (256 threads) reduces all partials and writes the 4 outputs.
// 256 threads — minimum load-chain depth; the 64-thread variant (R3) was ~4us
// slower (24 serialized strided loads per lane vs 6 here).
__global__ void k_fin(const float* __restrict__ ws, float* __restrict__ out) {
    float coord_s = 0.0f, confc_s = 0.0f, cls_s = 0.0f, cnt_s = 0.0f, sp_s = 0.0f;
    for (int i = threadIdx.x; i < OBJ_BLOCKS; i += 256) {
        coord_s += ws[0 * OBJ_BLOCKS + i];
        confc_s += ws[1 * OBJ_BLOCKS + i];
        cls_s   += ws[2 * OBJ_BLOCKS + i];
        cnt_s   += ws[3 * OBJ_BLOCKS + i];
    }
    for (int i = threadIdx.x; i < MAIN_BLOCKS; i += 256) {
        sp_s += ws[WS_SP_OFF + i];
    }
#pragma unroll
    for (int o = 32; o > 0; o >>= 1) {
        coord_s += __shfl_down(coord_s, o);
        confc_s += __shfl_down(confc_s, o);
        cls_s   += __shfl_down(cls_s,   o);
        cnt_s   += __shfl_down(cnt_s,   o);
        sp_s    += __shfl_down(sp_s,    o);
    }
    __shared__ float ls[4][5];
    int lane = threadIdx.x & 63, wav = threadIdx.x >> 6;
    if (lane == 0) {
        ls[wav][0] = coord_s; ls[wav][1] = confc_s; ls[wav][2] = cls_s;
        ls[wav][3] = cnt_s;   ls[wav][4] = sp_s;
    }
    __syncthreads();
    if (threadIdx.x == 0) {
        float coord = ls[0][0] + ls[1][0] + ls[2][0] + ls[3][0];
        float confc = ls[0][1] + ls[1][1] + ls[2][1] + ls[3][1];
        float cls   = ls[0][2] + ls[1][2] + ls[2][2] + ls[3][2];
        float cnt   = ls[0][3] + ls[1][3] + ls[2][3] + ls[3][3];
        float sp    = ls[0][4] + ls[1][4] + ls[2][4] + ls[3][4];
        float n_obj = fmaxf(cnt, 1.0f);
        float coord_loss = 0.05f * coord / (n_obj * 4.0f);
        float conf_loss  = (sp + confc) / (float)MROWS;
        float class_loss = 0.5f * cls / (n_obj * (float)NUM_CLASSES);
        out[0] = coord_loss + conf_loss + class_loss;
        out[1] = coord_loss;
        out[2] = conf_loss;
        out[3] = class_loss;
    }
}

extern "C" void kernel_launch(void* const* d_in, const int* in_sizes, int n_in,
                              void* d_out, int out_size, void* d_ws, size_t ws_size,
                              hipStream_t stream) {
    const float* p0      = (const float*)d_in[0];
    const float* p1      = (const float*)d_in[1];
    const float* p2      = (const float*)d_in[2];
    const float* bboxes  = (const float*)d_in[3];
    const int*   labels  = (const int*)d_in[4];
    const float* anchors = (const float*)d_in[5];
    float* ws  = (float*)d_ws;
    float* out = (float*)d_out;

    k_main<<<MAIN_BLOCKS, 256, 0, stream>>>(p0, p1, p2, bboxes, labels, anchors, ws);
    k_fin<<<1, 256, 0, stream>>>(ws, out);
}